// Round 3
// baseline (13247.427 us; speedup 1.0000x reference)
//
#include <hip/hip_runtime.h>

#define T_STEPS 256
#define H1 5
#define H2 100
#define NS 2   // batch streams per block (share w2 registers, 2x ILP)

// tanh(x) = 1 - 2/(exp(2x)+1); saturates correctly for |x| large.
__device__ __forceinline__ float fast_tanh(float v) {
    float e = __expf(2.0f * v);
    return 1.0f - 2.0f * __builtin_amdgcn_rcpf(e + 1.0f);
}

// One block per 2 batch elements. 128 threads = 2 waves.
// lane j (< 100): owns row j of Whh2/Wih2 in registers; computes h2[j] for
//   both streams each step, reading shared state as uniform LDS broadcasts.
// lanes 100..109: run the 5-dim layer-1 recurrence one step ahead.
// x rows preloaded to LDS (kills the per-step global-load latency).
__global__ __launch_bounds__(128, 4) void rnn_fused2(
    const float* __restrict__ x,
    const float* __restrict__ Wih1, const float* __restrict__ Whh1,
    const float* __restrict__ bih1, const float* __restrict__ bhh1,
    const float* __restrict__ Wih2, const float* __restrict__ Whh2,
    const float* __restrict__ bih2, const float* __restrict__ bhh2,
    const float* __restrict__ W3,   const float* __restrict__ b3,
    float* __restrict__ out)
{
    const int bbase = blockIdx.x * NS;
    const int tid   = threadIdx.x;          // 0..127
    const bool jact = (tid < H2);
    const int  jj   = jact ? tid : 0;

    __shared__ __align__(16) float xs[NS * T_STEPS];   // 2 KB
    __shared__ __align__(16) float h2s[2][NS][104];    // double-buffered state
    __shared__ __align__(16) float h1s[2][NS][8];      // padded (zeros 5..7)

    // ---- preload x: 2 rows = 512 floats = 128 float4 ----
    {
        const float4* xg  = reinterpret_cast<const float4*>(x + (size_t)bbase * T_STEPS);
        reinterpret_cast<float4*>(xs)[tid] = xg[tid];
    }

    // ---- per-lane layer-2 weight row (registers) ----
    float w2[H2];
    #pragma unroll
    for (int k4 = 0; k4 < H2 / 4; ++k4) {
        float4 v = *reinterpret_cast<const float4*>(Whh2 + jj * H2 + 4 * k4);
        w2[4 * k4 + 0] = v.x; w2[4 * k4 + 1] = v.y;
        w2[4 * k4 + 2] = v.z; w2[4 * k4 + 3] = v.w;
    }
    float wi2[H1];
    #pragma unroll
    for (int k = 0; k < H1; ++k) wi2[k] = Wih2[jj * H1 + k];
    const float bias2 = bih2[jj] + bhh2[jj];

    // ---- layer-1 lanes: tid 100..109 -> (stream ls, index li) ----
    const int  l1idx = tid - 100;
    const bool l1act = (l1idx >= 0) && (l1idx < NS * H1);
    const int  ls    = l1act ? (l1idx / H1) : 0;
    const int  li    = l1act ? (l1idx % H1) : 0;
    float w1[H1];
    #pragma unroll
    for (int k = 0; k < H1; ++k) w1[k] = Whh1[li * H1 + k];
    const float wi1 = Wih1[li];
    const float b1  = bih1[li] + bhh1[li];

    // ---- zero-init state buffers ----
    {
        float* p2 = &h2s[0][0][0];                 // 2*NS*104 = 416 floats
        for (int i = tid; i < 2 * NS * 104; i += 128) p2[i] = 0.0f;
        float* p1 = &h1s[0][0][0];                 // 2*NS*8 = 32 floats
        if (tid < 2 * NS * 8) p1[tid] = 0.0f;
    }
    __syncthreads();

    // h1_seq[0] = tanh(Wih1*x_0 + bih1 + bhh1)   (h1_{-1} = 0)
    if (l1act) {
        float u = wi1 * xs[ls * T_STEPS + 0] + b1;
        h1s[0][ls][li] = fast_tanh(u);
    }
    __syncthreads();

    // ---- main recurrence ----
    int cur = 0;
    for (int t = 0; t < T_STEPS; ++t) {
        const int nxt = cur ^ 1;

        float a0[NS], a1[NS];
        #pragma unroll
        for (int s = 0; s < NS; ++s) { a0[s] = bias2; a1[s] = 0.f; }

        // layer-1 input contribution (uniform broadcast reads)
        #pragma unroll
        for (int s = 0; s < NS; ++s) {
            const float4 hA = *reinterpret_cast<const float4*>(&h1s[cur][s][0]);
            const float  h4 = h1s[cur][s][4];
            a0[s] += wi2[0] * hA.x; a1[s] += wi2[1] * hA.y;
            a0[s] += wi2[2] * hA.z; a1[s] += wi2[3] * hA.w;
            a0[s] += wi2[4] * h4;
        }

        // recurrent matvec: k-outer, stream-inner for cross-stream ILP
        #pragma unroll
        for (int k4 = 0; k4 < H2 / 4; ++k4) {
            #pragma unroll
            for (int s = 0; s < NS; ++s) {
                const float4 hv = *reinterpret_cast<const float4*>(&h2s[cur][s][4 * k4]);
                a0[s] += w2[4 * k4 + 0] * hv.x;
                a1[s] += w2[4 * k4 + 1] * hv.y;
                a0[s] += w2[4 * k4 + 2] * hv.z;
                a1[s] += w2[4 * k4 + 3] * hv.w;
            }
        }

        float hn[NS];
        #pragma unroll
        for (int s = 0; s < NS; ++s)
            hn[s] = fast_tanh(a0[s] + a1[s]);

        // layer-1 recurrence for step t+1 (spare lanes, x from LDS)
        const bool dol1 = l1act && (t + 1 < T_STEPS);
        float u = 0.0f;
        if (dol1) {
            u = wi1 * xs[ls * T_STEPS + (t + 1)] + b1;
            #pragma unroll
            for (int k = 0; k < H1; ++k) u += w1[k] * h1s[cur][ls][k];
            u = fast_tanh(u);
        }

        if (jact) {
            #pragma unroll
            for (int s = 0; s < NS; ++s) h2s[nxt][s][tid] = hn[s];
        }
        if (dol1) h1s[nxt][ls][li] = u;
        __syncthreads();
        cur = nxt;
    }

    // ---- epilogue: out[b] = relu(W3 · h2_last + b3) ----
    if (tid < NS) {
        float sacc = b3[0];
        #pragma unroll 4
        for (int k = 0; k < H2; ++k) sacc += W3[k] * h2s[cur][tid][k];
        out[bbase + tid] = fmaxf(sacc, 0.0f);
    }
}

extern "C" void kernel_launch(void* const* d_in, const int* in_sizes, int n_in,
                              void* d_out, int out_size, void* d_ws, size_t ws_size,
                              hipStream_t stream) {
    const float* x    = (const float*)d_in[0];
    const float* Wih1 = (const float*)d_in[1];
    const float* Whh1 = (const float*)d_in[2];
    const float* bih1 = (const float*)d_in[3];
    const float* bhh1 = (const float*)d_in[4];
    const float* Wih2 = (const float*)d_in[5];
    const float* Whh2 = (const float*)d_in[6];
    const float* bih2 = (const float*)d_in[7];
    const float* bhh2 = (const float*)d_in[8];
    const float* W3   = (const float*)d_in[9];
    const float* b3   = (const float*)d_in[10];
    float* out = (float*)d_out;

    const int B = in_sizes[0] / T_STEPS;   // 4096
    rnn_fused2<<<B / NS, 128, 0, stream>>>(x, Wih1, Whh1, bih1, bhh1,
                                           Wih2, Whh2, bih2, bhh2, W3, b3, out);
}

// Round 4
// 663.274 us; speedup vs baseline: 19.9728x; 19.9728x over previous
//
#include <hip/hip_runtime.h>

#define T_STEPS 256
#define H1 5
#define H2 100

typedef float f32x2 __attribute__((ext_vector_type(2)));

// tanh(x) = 1 - 2/(exp(2x)+1); saturates correctly for |x| large.
__device__ __forceinline__ float fast_tanh(float v) {
    float e = __expf(2.0f * v);
    return 1.0f - 2.0f * __builtin_amdgcn_rcpf(e + 1.0f);
}

// One block per batch element. 128 threads = 2 waves.
// lane j (< 100): owns row j of Whh2/Wih2, stored as 50 k-paired f32x2 in
//   registers; per step 50 v_pk_fma_f32 against uniform float4 broadcasts of
//   the LDS-resident h2 state (conflict-free).
// lanes 100..104: run the 5-dim layer-1 recurrence one step ahead, x from LDS.
__global__ __launch_bounds__(128) void rnn_pk(
    const float* __restrict__ x,
    const float* __restrict__ Wih1, const float* __restrict__ Whh1,
    const float* __restrict__ bih1, const float* __restrict__ bhh1,
    const float* __restrict__ Wih2, const float* __restrict__ Whh2,
    const float* __restrict__ bih2, const float* __restrict__ bhh2,
    const float* __restrict__ W3,   const float* __restrict__ b3,
    float* __restrict__ out)
{
    const int b   = blockIdx.x;
    const int tid = threadIdx.x;            // 0..127
    const bool jact = (tid < H2);
    const int  jj   = jact ? tid : 0;

    __shared__ __align__(16) float xs[T_STEPS];     // 1 KB
    __shared__ __align__(16) float h2s[2][104];     // double-buffered state
    __shared__ __align__(16) float h1s[2][8];       // padded (zeros 5..7)

    // ---- preload x row: 256 floats = 64 float4 ----
    if (tid < 64) {
        reinterpret_cast<float4*>(xs)[tid] =
            reinterpret_cast<const float4*>(x + (size_t)b * T_STEPS)[tid];
    }

    // ---- per-lane layer-2 weight row as 50 k-paired f32x2 (registers) ----
    f32x2 w2p[H2 / 2];
    #pragma unroll
    for (int k4 = 0; k4 < H2 / 4; ++k4) {
        float4 v = *reinterpret_cast<const float4*>(Whh2 + jj * H2 + 4 * k4);
        w2p[2 * k4 + 0] = f32x2{v.x, v.y};
        w2p[2 * k4 + 1] = f32x2{v.z, v.w};
    }
    f32x2 wi2p[4];   // Wih2 row padded 5 -> 8 with zeros
    #pragma unroll
    for (int p = 0; p < 4; ++p) {
        float e0 = (2 * p + 0 < H1) ? Wih2[jj * H1 + 2 * p + 0] : 0.0f;
        float e1 = (2 * p + 1 < H1) ? Wih2[jj * H1 + 2 * p + 1] : 0.0f;
        wi2p[p] = f32x2{e0, e1};
    }
    const float bias2 = bih2[jj] + bhh2[jj];

    // ---- layer-1 lanes: tid 100..104 ----
    const int  li0   = tid - 100;
    const bool l1act = (li0 >= 0) && (li0 < H1);
    const int  li    = l1act ? li0 : 0;
    float w1[H1];
    #pragma unroll
    for (int k = 0; k < H1; ++k) w1[k] = Whh1[li * H1 + k];
    const float wi1 = Wih1[li];
    const float b1  = bih1[li] + bhh1[li];

    // ---- zero-init state ----
    if (tid < 104) { h2s[0][tid] = 0.0f; h2s[1][tid] = 0.0f; }
    if (tid < 16)  { (&h1s[0][0])[tid] = 0.0f; }
    __syncthreads();
    if (l1act) {   // h1_seq[0] = tanh(Wih1*x_0 + b1)   (h1_{-1}=0)
        h1s[0][li] = fast_tanh(wi1 * xs[0] + b1);
    }
    __syncthreads();

    // ---- main recurrence ----
    int cur = 0;
    for (int t = 0; t < T_STEPS; ++t) {
        const int nxt = cur ^ 1;

        f32x2 accA = f32x2{bias2, 0.0f};
        f32x2 accB = f32x2{0.0f, 0.0f};

        // layer-1 input term (padded-8 uniform broadcast)
        {
            const float4 hA = *reinterpret_cast<const float4*>(&h1s[cur][0]);
            const float4 hB = *reinterpret_cast<const float4*>(&h1s[cur][4]);
            accA = __builtin_elementwise_fma(wi2p[0], f32x2{hA.x, hA.y}, accA);
            accB = __builtin_elementwise_fma(wi2p[1], f32x2{hA.z, hA.w}, accB);
            accA = __builtin_elementwise_fma(wi2p[2], f32x2{hB.x, hB.y}, accA);
            accB = __builtin_elementwise_fma(wi2p[3], f32x2{hB.z, hB.w}, accB);
        }

        // recurrent matvec: 25 uniform float4 reads, 50 packed FMAs
        #pragma unroll
        for (int k4 = 0; k4 < H2 / 4; ++k4) {
            const float4 hv = *reinterpret_cast<const float4*>(&h2s[cur][4 * k4]);
            accA = __builtin_elementwise_fma(w2p[2 * k4 + 0], f32x2{hv.x, hv.y}, accA);
            accB = __builtin_elementwise_fma(w2p[2 * k4 + 1], f32x2{hv.z, hv.w}, accB);
        }

        const float hn = fast_tanh((accA.x + accB.x) + (accA.y + accB.y));

        // layer-1 recurrence for step t+1 (spare lanes, x from LDS)
        const bool dol1 = l1act && (t + 1 < T_STEPS);
        float u = 0.0f;
        if (dol1) {
            u = wi1 * xs[t + 1] + b1;
            #pragma unroll
            for (int k = 0; k < H1; ++k) u += w1[k] * h1s[cur][k];
            u = fast_tanh(u);
        }

        if (jact) h2s[nxt][tid] = hn;
        if (dol1) h1s[nxt][li]  = u;
        __syncthreads();
        cur = nxt;
    }

    // ---- epilogue: out[b] = relu(W3 · h2_last + b3) ----
    if (tid == 0) {
        float sacc = b3[0];
        #pragma unroll 4
        for (int k = 0; k < H2; ++k) sacc += W3[k] * h2s[cur][k];
        out[b] = fmaxf(sacc, 0.0f);
    }
}

extern "C" void kernel_launch(void* const* d_in, const int* in_sizes, int n_in,
                              void* d_out, int out_size, void* d_ws, size_t ws_size,
                              hipStream_t stream) {
    const float* x    = (const float*)d_in[0];
    const float* Wih1 = (const float*)d_in[1];
    const float* Whh1 = (const float*)d_in[2];
    const float* bih1 = (const float*)d_in[3];
    const float* bhh1 = (const float*)d_in[4];
    const float* Wih2 = (const float*)d_in[5];
    const float* Whh2 = (const float*)d_in[6];
    const float* bih2 = (const float*)d_in[7];
    const float* bhh2 = (const float*)d_in[8];
    const float* W3   = (const float*)d_in[9];
    const float* b3   = (const float*)d_in[10];
    float* out = (float*)d_out;

    const int B = in_sizes[0] / T_STEPS;   // 4096
    rnn_pk<<<B, 128, 0, stream>>>(x, Wih1, Whh1, bih1, bhh1,
                                  Wih2, Whh2, bih2, bhh2, W3, b3, out);
}